// Round 1
// baseline (355.213 us; speedup 1.0000x reference)
//
#include <hip/hip_runtime.h>
#include <stdint.h>

// MultiHeadAttention  B=8, S=2048, D=768  (fp32 in/out; bf16 MFMA compute)
//
// Pipeline:
//   convert : all 9 fp32 inputs -> bf16 in ws
//   qkv_k   : fused Q/K/V projections (grid 64x9); V stored transposed Vt[b][e][s]
//   score_k : E = exp(min(Q.K^T/sqrt(D),30)) bf16 + fused rowsum atomicAdd -> rl
//   pv_k    : attn = (E @ V) * rcp(rl)
//   out_k   : out = attn@Wp^T + bp  (fp32)
//
// *** This round: 256x256 / BK=64 / 8-wave / 8-phase GEMM core (T2+T3+T4+T5) ***
// Replaces the m97-style 128^2 2-barrier core (ceiling ~700-900 TF here).
// - 8 waves (512 thr) as 2Mx4N; per-wave 128x64 out; acc[8][4] f32x4.
// - LDS 128KiB: 2 dbuf x (A 256x64 + B 256x64) bf16, row-major [256][8 slots].
// - T2 swizzle: slot' = slot ^ (row&7) (8 slots -> 2-way conflicts = free).
//   global_load_lds writes linearly, so the SOURCE k-slot is pre-swizzled and
//   reads apply the same XOR (both-sides rule, m104/m231).
// - T3/T4: per phase {ds_read subtile; stage 1 quarter-pair (2 loads); counted
//   vmcnt; s_barrier; lgkmcnt(0); setprio(1); 16 MFMA; setprio(0); s_barrier}.
//   Prefetch ~1.5 K-tiles deep; vmcnt(10) @ph2, vmcnt(6) @ph4; drain only at tail.
// Epilogues stage C through LDS [128][264] (bf16) / [64][264] (fp32), 16B stores.

typedef __attribute__((ext_vector_type(8))) short short8;
typedef __attribute__((ext_vector_type(4))) float f32x4;

typedef const __attribute__((address_space(1))) void gvoid_t;
typedef __attribute__((address_space(3))) void lvoid_t;

__device__ __forceinline__ float b2f(unsigned short u) {
  union { unsigned int u; float f; } v;
  v.u = ((unsigned int)u) << 16;
  return v.f;
}
__device__ __forceinline__ unsigned short f2b(float f) {
  union { float f; unsigned int u; } v; v.f = f;
  unsigned int u = v.u;
  return (unsigned short)((u + 0x7fffu + ((u >> 16) & 1u)) >> 16);
}

// ---------------- fp32 -> bf16 conversion ----------------
struct Cvt9 {
  const void* s[9];
  unsigned short* d[9];
  long long n8[9];
  long long total8;
};

__global__ __launch_bounds__(256) void convert_inputs(Cvt9 C) {
  long long g = (long long)blockIdx.x * 256 + threadIdx.x;
  if (g >= C.total8) return;
  int s = 0;
  long long off = g;
  while (off >= C.n8[s]) { off -= C.n8[s]; ++s; }
  const float* sf = (const float*)C.s[s] + off * 8;
  unsigned short* dp = C.d[s] + off * 8;
  float4 a = ((const float4*)sf)[0];
  float4 b = ((const float4*)sf)[1];
  uint4 o;
  o.x = (unsigned int)f2b(a.x) | ((unsigned int)f2b(a.y) << 16);
  o.y = (unsigned int)f2b(a.z) | ((unsigned int)f2b(a.w) << 16);
  o.z = (unsigned int)f2b(b.x) | ((unsigned int)f2b(b.y) << 16);
  o.w = (unsigned int)f2b(b.z) | ((unsigned int)f2b(b.w) << 16);
  *(uint4*)dp = o;
}

// ---------------- 256x256 8-phase GEMM core ----------------
// C[m0..+256][n0..+256] += A[m0..][0..K) . B[n0..][0..K)^T   (both NT, bf16)
// LDS layout (shorts): buf b: A at b*32768 (256 rows x 64), B at b*32768+16384.
// Quarter q (64 rows) = one stage round region of 4096 shorts.
__device__ __forceinline__ void gemm256(
    const unsigned short* __restrict__ Ag,   // pre-offset to (m0, 0), lda shorts
    const unsigned short* __restrict__ Bg,   // pre-offset to (n0, 0), ldb shorts
    const int lda, const int ldb, const int NT,
    unsigned short* lds, f32x4 (&acc)[8][4])
{
  const int t    = threadIdx.x;
  const int w    = t >> 6;
  const int lane = t & 63;
  const int lo   = lane & 15;
  const int quad = lane >> 4;
  const int wr   = w >> 2;          // 0..1  (row half of C tile)
  const int wcn  = w & 3;           // 0..3  (col quarter of C tile)
  const int swz  = ((t & 7) ^ ((t >> 3) & 7)) << 3;   // pre-swizzled src k-slot (shorts)
  const int wslot = w * 512;                          // wave slot in a stage round
  const int sl0  = (quad ^ (lo & 7)) << 3;            // read slot, k-chunk 0
  const int sl1  = ((4 + quad) ^ (lo & 7)) << 3;      // read slot, k-chunk 1
  const unsigned short* pA = lds + wr * 8192 + lo * 64;
  const unsigned short* pB = lds + 16384 + (wcn >> 1) * 8192 + ((wcn & 1) * 64 + lo) * 64;

  short8 af[4][2], bf0[2][2], bf1[2][2];

#define STG(gb, ld, kt, q, reg)                                                   \
  __builtin_amdgcn_global_load_lds(                                               \
      (gvoid_t*)((gb) + (size_t)((q) * 64 + (t >> 3)) * (ld) + (kt) * 64 + swz),  \
      (lvoid_t*)((reg) + wslot), 16, 0, 0)
#define SA02(kt) { unsigned short* r_ = lds + ((kt) & 1) * 32768;         \
                   STG(Ag, lda, (kt), 0, r_); STG(Ag, lda, (kt), 2, r_ + 8192); }
#define SA13(kt) { unsigned short* r_ = lds + ((kt) & 1) * 32768;         \
                   STG(Ag, lda, (kt), 1, r_ + 4096); STG(Ag, lda, (kt), 3, r_ + 12288); }
#define SB01(kt) { unsigned short* r_ = lds + ((kt) & 1) * 32768 + 16384; \
                   STG(Bg, ldb, (kt), 0, r_); STG(Bg, ldb, (kt), 1, r_ + 4096); }
#define SB23(kt) { unsigned short* r_ = lds + ((kt) & 1) * 32768 + 16384; \
                   STG(Bg, ldb, (kt), 2, r_ + 8192); STG(Bg, ldb, (kt), 3, r_ + 12288); }
#define RDA(MH, pAb) { _Pragma("unroll") for (int mi = 0; mi < 4; ++mi) {     \
    af[mi][0] = *(const short8*)((pAb) + (MH) * 4096 + mi * 1024 + sl0);      \
    af[mi][1] = *(const short8*)((pAb) + (MH) * 4096 + mi * 1024 + sl1); } }
#define RDB(BF, NH, pBb) { _Pragma("unroll") for (int ni = 0; ni < 2; ++ni) { \
    BF[ni][0] = *(const short8*)((pBb) + (NH) * 2048 + ni * 1024 + sl0);      \
    BF[ni][1] = *(const short8*)((pBb) + (NH) * 2048 + ni * 1024 + sl1); } }
#define MMA(MH, NH, BF) {                                                     \
  __builtin_amdgcn_s_barrier();                                               \
  asm volatile("s_waitcnt lgkmcnt(0)" ::: "memory");                          \
  __builtin_amdgcn_s_setprio(1);                                              \
  _Pragma("unroll") for (int kc = 0; kc < 2; ++kc)                            \
  _Pragma("unroll") for (int mi = 0; mi < 4; ++mi)                            \
  _Pragma("unroll") for (int ni = 0; ni < 2; ++ni)                            \
    acc[(MH)*4 + mi][(NH)*2 + ni] = __builtin_amdgcn_mfma_f32_16x16x32_bf16(  \
        af[mi][kc], BF[ni][kc], acc[(MH)*4 + mi][(NH)*2 + ni], 0, 0, 0);      \
  __builtin_amdgcn_s_setprio(0);                                              \
  __builtin_amdgcn_s_barrier(); }
#define VM(n) asm volatile("s_waitcnt vmcnt(" #n ")" ::: "memory")

  // prologue: tile0 fully + tile1 A02/B01/A13 (B23 comes at loop ph1)
  SA02(0); SB01(0); SA13(0); SB23(0);
  SA02(1); SB01(1); SA13(1);
  VM(6);
  __builtin_amdgcn_s_barrier();

  for (int kt = 0; kt < NT - 2; ++kt) {
    const unsigned short* pAb = pA + (kt & 1) * 32768;
    const unsigned short* pBb = pB + (kt & 1) * 32768;
    // ph1: quad (m0,n0)
    RDA(0, pAb); RDB(bf0, 0, pBb); SB23(kt + 1);          MMA(0, 0, bf0);
    // ph2: quad (m0,n1)
    RDB(bf1, 1, pBb);              SA02(kt + 2); VM(10);  MMA(0, 1, bf1);
    // ph3: quad (m1,n0)
    RDA(1, pAb);                   SB01(kt + 2);          MMA(1, 0, bf0);
    // ph4: quad (m1,n1)
                                   SA13(kt + 2); VM(6);   MMA(1, 1, bf1);
  }
  { // kt = NT-2: last prefetch is (NT-1)B23; drain to 0 entering final tile
    const int kt = NT - 2;
    const unsigned short* pAb = pA + (kt & 1) * 32768;
    const unsigned short* pBb = pB + (kt & 1) * 32768;
    RDA(0, pAb); RDB(bf0, 0, pBb); SB23(kt + 1);          MMA(0, 0, bf0);
    RDB(bf1, 1, pBb);                            VM(8);   MMA(0, 1, bf1);
    RDA(1, pAb);                                          MMA(1, 0, bf0);
                                                 VM(0);   MMA(1, 1, bf1);
  }
  { // kt = NT-1: all data resident
    const int kt = NT - 1;
    const unsigned short* pAb = pA + (kt & 1) * 32768;
    const unsigned short* pBb = pB + (kt & 1) * 32768;
    RDA(0, pAb); RDB(bf0, 0, pBb);                        MMA(0, 0, bf0);
    RDB(bf1, 1, pBb);                                     MMA(0, 1, bf1);
    RDA(1, pAb);                                          MMA(1, 0, bf0);
                                                          MMA(1, 1, bf1);
  }
#undef STG
#undef SA02
#undef SA13
#undef SB01
#undef SB23
#undef RDA
#undef RDB
#undef MMA
#undef VM
}

// ---------------- bf16 epilogue: stage half-tile rows [h*128, h*128+128) ----------------
// MODE 0: v += bias ; MODE 2: v = exp(min(v*scale,30)) ; MODE 3: v *= rcp(rl[row])
template<int MODE>
__device__ __forceinline__ void epi_bf16(
    unsigned short* Ls, f32x4 (&acc)[8][4], int h,
    const unsigned short* bias_n0, const float* rlbase, float scale,
    unsigned short* Cg, int ldc)
{
  const int t = threadIdx.x, w = t >> 6, lane = t & 63;
  const int lo = lane & 15, quad = lane >> 4, wr = w >> 2, wcn = w & 3;
  __syncthreads();
  if (wr == h) {
    float bvv[4];
    if (MODE == 0) {
#pragma unroll
      for (int nf = 0; nf < 4; ++nf) bvv[nf] = b2f(bias_n0[wcn * 64 + nf * 16 + lo]);
    }
#pragma unroll
    for (int mf = 0; mf < 8; ++mf) {
      const int r0 = mf * 16 + quad * 4;
      float rv[4];
      if (MODE == 3) {
#pragma unroll
        for (int r = 0; r < 4; ++r) rv[r] = __builtin_amdgcn_rcpf(rlbase[h * 128 + r0 + r]);
      }
#pragma unroll
      for (int nf = 0; nf < 4; ++nf) {
        const int col = wcn * 64 + nf * 16 + lo;
#pragma unroll
        for (int r = 0; r < 4; ++r) {
          float v = acc[mf][nf][r];
          if (MODE == 0)      v += bvv[nf];
          else if (MODE == 2) v = __expf(fminf(v * scale, 30.f));
          else if (MODE == 3) v *= rv[r];
          Ls[(r0 + r) * 264 + col] = f2b(v);
        }
      }
    }
  }
  __syncthreads();
#pragma unroll
  for (int u0 = 0; u0 < 8; ++u0) {
    const int u = u0 * 512 + t, row = u >> 5, c16 = (u & 31) * 8;
    *(uint4*)(Cg + (size_t)(h * 128 + row) * ldc + c16) = *(const uint4*)(Ls + row * 264 + c16);
  }
}

// ---------------- qkv: fused projections ----------------
__global__ __launch_bounds__(512, 2) void qkv_k(
    const unsigned short* __restrict__ xb,
    const unsigned short* __restrict__ Wq, const unsigned short* __restrict__ bq,
    const unsigned short* __restrict__ Wk, const unsigned short* __restrict__ bk,
    const unsigned short* __restrict__ Wv, const unsigned short* __restrict__ bv,
    unsigned short* __restrict__ qb, unsigned short* __restrict__ kb,
    unsigned short* __restrict__ vt)
{
  __shared__ unsigned short smem[65536];
  const int sel = blockIdx.y / 3;
  const int n0  = (blockIdx.y % 3) * 256;
  const int m0  = blockIdx.x * 256;

  const unsigned short* W;
  const unsigned short* bi;
  if (sel == 0)      { W = Wq; bi = bq; }
  else if (sel == 1) { W = Wk; bi = bk; }
  else               { W = Wv; bi = bv; }

  f32x4 acc[8][4] = {};
  gemm256(xb + (size_t)m0 * 768, W + (size_t)n0 * 768, 768, 768, 12, smem, acc);

  if (sel < 2) {
    unsigned short* dst = (sel == 0 ? qb : kb) + (size_t)m0 * 768 + n0;
    epi_bf16<0>(smem, acc, 0, bi + n0, nullptr, 0.f, dst, 768);
    epi_bf16<0>(smem, acc, 1, bi + n0, nullptr, 0.f, dst, 768);
    return;
  }

  // V: transposed epilogue into Vt[b][e][s]; Ls as [e_local 128][s 264]
  const int t = threadIdx.x, w = t >> 6, lane = t & 63;
  const int lo = lane & 15, quad = lane >> 4, wr = w >> 2, wcn = w & 3;
  const int bb2 = m0 >> 11, sin = m0 & 2047;
  unsigned short* Ls = smem;
#pragma unroll
  for (int eh = 0; eh < 2; ++eh) {
    __syncthreads();
    if ((wcn >> 1) == eh) {
#pragma unroll
      for (int mf = 0; mf < 8; ++mf) {
        const int row = wr * 128 + mf * 16 + quad * 4;
#pragma unroll
        for (int nf = 0; nf < 4; ++nf) {
          const int colL = (wcn & 1) * 64 + nf * 16 + lo;
          const float bvv = b2f(bi[n0 + eh * 128 + colL]);
          ushort4 pk;
          pk.x = f2b(acc[mf][nf][0] + bvv);
          pk.y = f2b(acc[mf][nf][1] + bvv);
          pk.z = f2b(acc[mf][nf][2] + bvv);
          pk.w = f2b(acc[mf][nf][3] + bvv);
          *(ushort4*)(Ls + colL * 264 + row) = pk;
        }
      }
    }
    __syncthreads();
    unsigned short* Vb = vt + (size_t)bb2 * 1572864 + (size_t)(n0 + eh * 128) * 2048 + sin;
#pragma unroll
    for (int u0 = 0; u0 < 8; ++u0) {
      const int u = u0 * 512 + t, e = u >> 5, s16 = (u & 31) * 8;
      *(uint4*)(Vb + (size_t)e * 2048 + s16) = *(const uint4*)(Ls + e * 264 + s16);
    }
  }
}

// ---------------- score: E = exp(QK^T/sqrt(D)) + fused rowsum ----------------
__global__ __launch_bounds__(512, 2) void score_k(
    const unsigned short* __restrict__ Q, const unsigned short* __restrict__ Kb,
    unsigned short* __restrict__ E, float* __restrict__ rl, float scale)
{
  __shared__ unsigned short smem[65536];
  const int m0 = blockIdx.x * 256, n0 = blockIdx.y * 256, bz = blockIdx.z;

  f32x4 acc[8][4] = {};
  gemm256(Q + (size_t)bz * 1572864 + (size_t)m0 * 768,
          Kb + (size_t)bz * 1572864 + (size_t)n0 * 768, 768, 768, 12, smem, acc);

  const int t = threadIdx.x;
  unsigned short* Eg = E + (size_t)bz * 4194304 + (size_t)m0 * 2048 + n0;
#pragma unroll
  for (int h = 0; h < 2; ++h) {
    epi_bf16<2>(smem, acc, h, nullptr, nullptr, scale, Eg, 2048);
    // fused partial rowsum from staged LDS tile (4 threads/row, rotated reads)
    const int row = t >> 2, seg = t & 3;
    const unsigned short* lr = smem + row * 264 + seg * 64;
    float s = 0.f;
#pragma unroll
    for (int q8 = 0; q8 < 8; ++q8) {
      const int qq = ((q8 + row) & 7) * 8;
      uint4 v = *(const uint4*)(lr + qq);
      unsigned int uu[4] = {v.x, v.y, v.z, v.w};
#pragma unroll
      for (int c = 0; c < 4; ++c)
        s += b2f((unsigned short)(uu[c] & 0xffffu)) + b2f((unsigned short)(uu[c] >> 16));
    }
    s += __shfl_xor(s, 1);
    s += __shfl_xor(s, 2);
    if (seg == 0) atomicAdd(rl + bz * 2048 + m0 + h * 128 + row, s);
  }
}

// ---------------- pv: attn = (E @ V) * rcp(rowsum) ----------------
__global__ __launch_bounds__(512, 2) void pv_k(
    const unsigned short* __restrict__ E, const unsigned short* __restrict__ Vt,
    const float* __restrict__ rl, unsigned short* __restrict__ attn)
{
  __shared__ unsigned short smem[65536];
  const int m0 = blockIdx.x * 256, n0 = blockIdx.y * 256, bz = blockIdx.z;

  f32x4 acc[8][4] = {};
  gemm256(E + (size_t)bz * 4194304 + (size_t)m0 * 2048,
          Vt + (size_t)bz * 1572864 + (size_t)n0 * 2048, 2048, 2048, 32, smem, acc);

  const float* rlb = rl + bz * 2048 + m0;
  unsigned short* Cg = attn + (size_t)bz * 1572864 + (size_t)m0 * 768 + n0;
  epi_bf16<3>(smem, acc, 0, nullptr, rlb, 0.f, Cg, 768);
  epi_bf16<3>(smem, acc, 1, nullptr, rlb, 0.f, Cg, 768);
}

// ---------------- out: final projection (fp32 output) ----------------
__global__ __launch_bounds__(512, 2) void out_k(
    const unsigned short* __restrict__ attn,
    const unsigned short* __restrict__ Wp, const unsigned short* __restrict__ bp,
    float* __restrict__ Of)
{
  __shared__ unsigned short smem[65536];
  const int m0 = blockIdx.x * 256, n0 = blockIdx.y * 256;

  f32x4 acc[8][4] = {};
  gemm256(attn + (size_t)m0 * 768, Wp + (size_t)n0 * 768, 768, 768, 12, smem, acc);

  const int t = threadIdx.x, w = t >> 6, lane = t & 63;
  const int lo = lane & 15, quad = lane >> 4, wr = w >> 2, wcn = w & 3;
  float* Lf = (float*)smem;  // [64][264] floats per pass
#pragma unroll
  for (int p = 0; p < 4; ++p) {
    __syncthreads();
    if (wr == (p >> 1)) {
#pragma unroll
      for (int mi = 0; mi < 4; ++mi) {
        const int mf = (p & 1) * 4 + mi;
        const int r0 = mi * 16 + quad * 4;
#pragma unroll
        for (int nf = 0; nf < 4; ++nf) {
          const int col = wcn * 64 + nf * 16 + lo;
          const float bvv = b2f(bp[n0 + col]);
#pragma unroll
          for (int r = 0; r < 4; ++r)
            Lf[(r0 + r) * 264 + col] = acc[mf][nf][r] + bvv;
        }
      }
    }
    __syncthreads();
#pragma unroll
    for (int u0 = 0; u0 < 8; ++u0) {
      const int u = u0 * 512 + t, row = u >> 6, c4 = (u & 63) * 4;
      *(float4*)(Of + (size_t)(m0 + p * 64 + row) * 768 + n0 + c4) =
          *(const float4*)(Lf + row * 264 + c4);
    }
  }
}

extern "C" void kernel_launch(void* const* d_in, const int* in_sizes, int n_in,
                              void* d_out, int out_size, void* d_ws, size_t ws_size,
                              hipStream_t stream) {
  (void)in_sizes; (void)n_in; (void)out_size; (void)ws_size;

  char* ws = (char*)d_ws;
  float* rl    = (float*)(ws + 4096);
  unsigned short* wcv = (unsigned short*)(ws + ((size_t)1 << 20));
  unsigned short* qb  = (unsigned short*)(ws + ((size_t)8  << 20));
  unsigned short* kb  = (unsigned short*)(ws + ((size_t)32 << 20));
  unsigned short* vt  = (unsigned short*)(ws + ((size_t)56 << 20));
  unsigned short* eb  = (unsigned short*)(ws + ((size_t)80 << 20));
  unsigned short* xb  = eb;     // converted x aliases E (x dead before score_k writes E)
  unsigned short* attn = qb;    // Q dead after score_k

  unsigned short* wqb = wcv;
  unsigned short* bqb = wcv + 589824;
  unsigned short* wkb = wcv + 590592;
  unsigned short* bkb = wcv + 1180416;
  unsigned short* wvb = wcv + 1181184;
  unsigned short* bvb = wcv + 1771008;
  unsigned short* wpb = wcv + 1771776;
  unsigned short* bpb = wcv + 2361600;

  const float inv_scale = 0.036084391824351615f;  // 1/sqrt(768)

  Cvt9 cv;
  cv.s[0] = d_in[0]; cv.d[0] = xb;  cv.n8[0] = 12582912 / 8;
  cv.s[1] = d_in[1]; cv.d[1] = wqb; cv.n8[1] = 589824 / 8;
  cv.s[2] = d_in[2]; cv.d[2] = bqb; cv.n8[2] = 768 / 8;
  cv.s[3] = d_in[3]; cv.d[3] = wkb; cv.n8[3] = 589824 / 8;
  cv.s[4] = d_in[4]; cv.d[4] = bkb; cv.n8[4] = 768 / 8;
  cv.s[5] = d_in[5]; cv.d[5] = wvb; cv.n8[5] = 589824 / 8;
  cv.s[6] = d_in[6]; cv.d[6] = bvb; cv.n8[6] = 768 / 8;
  cv.s[7] = d_in[7]; cv.d[7] = wpb; cv.n8[7] = 589824 / 8;
  cv.s[8] = d_in[8]; cv.d[8] = bpb; cv.n8[8] = 768 / 8;
  cv.total8 = (12582912 + 4 * (589824 + 768)) / 8;
  convert_inputs<<<(unsigned)((cv.total8 + 255) / 256), dim3(256), 0, stream>>>(cv);

  hipMemsetAsync(rl, 0, 16384 * sizeof(float), stream);

  qkv_k<<<dim3(64, 9, 1), dim3(512), 0, stream>>>(xb, wqb, bqb, wkb, bkb, wvb, bvb, qb, kb, vt);

  score_k<<<dim3(8, 8, 8), dim3(512), 0, stream>>>(qb, kb, eb, rl, inv_scale);

  pv_k<<<dim3(8, 3, 8), dim3(512), 0, stream>>>(eb, vt, rl, attn);

  out_k<<<dim3(64, 3, 1), dim3(512), 0, stream>>>(attn, wpb, bpb, (float*)d_out);
}

// Round 2
// 353.844 us; speedup vs baseline: 1.0039x; 1.0039x over previous
//
#include <hip/hip_runtime.h>
#include <stdint.h>

// MultiHeadAttention  B=8, S=2048, D=768  (fp32 in/out; bf16 MFMA compute)
//
// Pipeline:
//   convert : all 9 fp32 inputs -> bf16 in ws
//   qkv_k   : fused Q/K/V projections (grid 64x9); V stored transposed Vt[b][e][s]
//   score_k : E = exp(min(Q.K^T/sqrt(D),30)) bf16 + fused rowsum atomicAdd -> rl
//   pv_k    : attn = (E @ V) * rcp(rl)
//   out_k   : out = attn@Wp^T + bp  (fp32)
//
// 256x256 / BK=64 / 8-wave / 4-phase-per-K-tile GEMM core (T2+T3+T4+T5).
// *** This round: inline-asm ds_read_b128 fragment loads (rule 18) ***
// R1 showed the counted-vmcnt pipeline collapsed (MfmaUtil 26%, ~1900 cyc/phase
// = full latency drain every phase): the memory legalizer cannot disprove
// aliasing between in-flight global_load_lds DMA writes and compiler-visible
// LDS loads, so it inserts s_waitcnt vmcnt(0) before every phase's ds_reads.
// Fix: fragment reads are inline-asm ds_read_b128 with manual
// {s_barrier; lgkmcnt(0); sched_barrier(0)} fencing; all vmcnt waits are the
// counted VM(8)/VM(0) of the schedule. Also: uniform prefetch (each quarter
// staged exactly one phase after its last read; B23 moved to ph3) -> 4-phase
// min slack, one VM(8) per K-tile.

typedef __attribute__((ext_vector_type(8))) short short8;
typedef __attribute__((ext_vector_type(4))) float f32x4;

typedef const __attribute__((address_space(1))) void gvoid_t;
typedef __attribute__((address_space(3))) void lvoid_t;

__device__ __forceinline__ float b2f(unsigned short u) {
  union { unsigned int u; float f; } v;
  v.u = ((unsigned int)u) << 16;
  return v.f;
}
__device__ __forceinline__ unsigned short f2b(float f) {
  union { float f; unsigned int u; } v; v.f = f;
  unsigned int u = v.u;
  return (unsigned short)((u + 0x7fffu + ((u >> 16) & 1u)) >> 16);
}

// ---------------- fp32 -> bf16 conversion ----------------
struct Cvt9 {
  const void* s[9];
  unsigned short* d[9];
  long long n8[9];
  long long total8;
};

__global__ __launch_bounds__(256) void convert_inputs(Cvt9 C) {
  long long g = (long long)blockIdx.x * 256 + threadIdx.x;
  if (g >= C.total8) return;
  int s = 0;
  long long off = g;
  while (off >= C.n8[s]) { off -= C.n8[s]; ++s; }
  const float* sf = (const float*)C.s[s] + off * 8;
  unsigned short* dp = C.d[s] + off * 8;
  float4 a = ((const float4*)sf)[0];
  float4 b = ((const float4*)sf)[1];
  uint4 o;
  o.x = (unsigned int)f2b(a.x) | ((unsigned int)f2b(a.y) << 16);
  o.y = (unsigned int)f2b(a.z) | ((unsigned int)f2b(a.w) << 16);
  o.z = (unsigned int)f2b(b.x) | ((unsigned int)f2b(b.y) << 16);
  o.w = (unsigned int)f2b(b.z) | ((unsigned int)f2b(b.w) << 16);
  *(uint4*)dp = o;
}

// ---------------- 256x256 4-phase/K-tile GEMM core ----------------
// C[m0..+256][n0..+256] += A[m0..][0..K) . B[n0..][0..K)^T   (both NT, bf16)
// LDS (bytes): buf b at b*65536: A 256x64 bf16 (32768 B) then B 256x64 (32768 B).
// Quarter q (64 rows) = one stage round region of 8192 B.
// T2 swizzle: 16B slot s of row r holds global k-slot s^(r&7); staged via
// pre-swizzled global source (both-sides rule), read via XOR'd byte address.
__device__ __forceinline__ void gemm256(
    const unsigned short* __restrict__ Ag,   // pre-offset to (m0, 0), lda shorts
    const unsigned short* __restrict__ Bg,   // pre-offset to (n0, 0), ldb shorts
    const int lda, const int ldb, const int NT,
    unsigned short* lds, f32x4 (&acc)[8][4])
{
  const int t    = threadIdx.x;
  const int w    = t >> 6;
  const int lane = t & 63;
  const int lo   = lane & 15;
  const int quad = lane >> 4;
  const int wr   = w >> 2;          // 0..1  (row half of C tile)
  const int wcn  = w & 3;           // 0..3  (col quarter of C tile)
  const int swz  = ((t & 7) ^ ((t >> 3) & 7)) << 3;   // pre-swizzled src k-slot (shorts)
  const int wslot = w * 512;                          // wave slot in a stage round (shorts)

  // LDS byte addresses for asm ds_read (low 32 bits of generic ptr = LDS offset)
  const unsigned lbase = (unsigned)(uintptr_t)(void*)lds;
  const unsigned sb0 = (unsigned)((quad ^ (lo & 7)) << 4);        // k-chunk 0 slot (bytes)
  const unsigned sb1 = (unsigned)(((4 + quad) ^ (lo & 7)) << 4);  // k-chunk 1 slot (bytes)
  const unsigned aA0 = lbase + wr * 16384 + lo * 128 + sb0;
  const unsigned aA1 = lbase + wr * 16384 + lo * 128 + sb1;
  const unsigned aB0 = lbase + 32768 + (wcn >> 1) * 16384 + ((wcn & 1) * 64 + lo) * 128 + sb0;
  const unsigned aB1 = lbase + 32768 + (wcn >> 1) * 16384 + ((wcn & 1) * 64 + lo) * 128 + sb1;

  short8 af[4][2], bf0[2][2], bf1[2][2];

#define STG(gb, ld, kt, q, reg)                                                   \
  __builtin_amdgcn_global_load_lds(                                               \
      (gvoid_t*)((gb) + (size_t)((q) * 64 + (t >> 3)) * (ld) + (kt) * 64 + swz),  \
      (lvoid_t*)((reg) + wslot), 16, 0, 0)
#define SA02(kt) { unsigned short* r_ = lds + ((kt) & 1) * 32768;         \
                   STG(Ag, lda, (kt), 0, r_); STG(Ag, lda, (kt), 2, r_ + 8192); }
#define SA13(kt) { unsigned short* r_ = lds + ((kt) & 1) * 32768;         \
                   STG(Ag, lda, (kt), 1, r_ + 4096); STG(Ag, lda, (kt), 3, r_ + 12288); }
#define SB01(kt) { unsigned short* r_ = lds + ((kt) & 1) * 32768 + 16384; \
                   STG(Bg, ldb, (kt), 0, r_); STG(Bg, ldb, (kt), 1, r_ + 4096); }
#define SB23(kt) { unsigned short* r_ = lds + ((kt) & 1) * 32768 + 16384; \
                   STG(Bg, ldb, (kt), 2, r_ + 8192); STG(Bg, ldb, (kt), 3, r_ + 12288); }
// inline-asm LDS fragment read: invisible to the memory legalizer (no auto vmcnt)
#define DSR(d, a, IMM) asm volatile("ds_read_b128 %0, %1 offset:" #IMM : "=v"(d) : "v"(a))
#define RDA(MH, bo) {                                                 \
  const unsigned a0_ = aA0 + (bo) + (MH) * 8192;                      \
  const unsigned a1_ = aA1 + (bo) + (MH) * 8192;                      \
  DSR(af[0][0], a0_, 0);    DSR(af[0][1], a1_, 0);                    \
  DSR(af[1][0], a0_, 2048); DSR(af[1][1], a1_, 2048);                 \
  DSR(af[2][0], a0_, 4096); DSR(af[2][1], a1_, 4096);                 \
  DSR(af[3][0], a0_, 6144); DSR(af[3][1], a1_, 6144); }
#define RDB(BF, NH, bo) {                                             \
  const unsigned b0_ = aB0 + (bo) + (NH) * 4096;                      \
  const unsigned b1_ = aB1 + (bo) + (NH) * 4096;                      \
  DSR(BF[0][0], b0_, 0);    DSR(BF[0][1], b1_, 0);                    \
  DSR(BF[1][0], b0_, 2048); DSR(BF[1][1], b1_, 2048); }
#define MMA(MH, NH, BF) {                                                     \
  __builtin_amdgcn_s_barrier();                                               \
  asm volatile("s_waitcnt lgkmcnt(0)" ::: "memory");                          \
  __builtin_amdgcn_sched_barrier(0);                                          \
  __builtin_amdgcn_s_setprio(1);                                              \
  _Pragma("unroll") for (int kc = 0; kc < 2; ++kc)                            \
  _Pragma("unroll") for (int mi = 0; mi < 4; ++mi)                            \
  _Pragma("unroll") for (int ni = 0; ni < 2; ++ni)                            \
    acc[(MH)*4 + mi][(NH)*2 + ni] = __builtin_amdgcn_mfma_f32_16x16x32_bf16(  \
        af[mi][kc], BF[ni][kc], acc[(MH)*4 + mi][(NH)*2 + ni], 0, 0, 0);      \
  __builtin_amdgcn_s_setprio(0);                                              \
  __builtin_amdgcn_sched_barrier(0);                                          \
  __builtin_amdgcn_s_barrier(); }
#define VM(n) asm volatile("s_waitcnt vmcnt(" #n ")" ::: "memory")

  // prologue: tiles 0 and 1 fully staged; wait tile 0 (8 newest stay in flight)
  SA02(0); SB01(0); SB23(0); SA13(0);
  SA02(1); SB01(1); SB23(1); SA13(1);
  VM(8);
  __builtin_amdgcn_s_barrier();

  // steady state: each quarter staged exactly one phase after its last read.
  // Invariant at iter entry: 8 outstanding = all of tile kt+1.
  for (int kt = 0; kt < NT - 2; ++kt) {
    const unsigned bo = (unsigned)(kt & 1) << 16;
    // ph1: reads A02(kt)+B(NH0)
    RDA(0, bo); RDB(bf0, 0, bo);                          MMA(0, 0, bf0);
    // ph2: reads B(NH1); stage A02(kt+2) (A02 last read ph1)
    RDB(bf1, 1, bo); SA02(kt + 2);                        MMA(0, 1, bf1);
    // ph3: reads A13(kt); stage B01+B23(kt+2) (B last read ph2)
    RDA(1, bo); SB01(kt + 2); SB23(kt + 2);               MMA(1, 0, bf0);
    // ph4: stage A13(kt+2) (A13 last read ph3); VM(8) completes tile kt+1
    SA13(kt + 2); VM(8);                                  MMA(1, 1, bf1);
  }
  { // kt = NT-2: no staging; drain remaining 8 (tile NT-1) at ph4
    const unsigned bo = (unsigned)(NT & 1) << 16;         // (NT-2)&1 == NT&1
    RDA(0, bo); RDB(bf0, 0, bo);                          MMA(0, 0, bf0);
    RDB(bf1, 1, bo);                                      MMA(0, 1, bf1);
    RDA(1, bo);                                           MMA(1, 0, bf0);
    VM(0);                                                MMA(1, 1, bf1);
  }
  { // kt = NT-1: all data resident
    const unsigned bo = (unsigned)((NT - 1) & 1) << 16;
    RDA(0, bo); RDB(bf0, 0, bo);                          MMA(0, 0, bf0);
    RDB(bf1, 1, bo);                                      MMA(0, 1, bf1);
    RDA(1, bo);                                           MMA(1, 0, bf0);
                                                          MMA(1, 1, bf1);
  }
#undef STG
#undef SA02
#undef SA13
#undef SB01
#undef SB23
#undef DSR
#undef RDA
#undef RDB
#undef MMA
#undef VM
}

// ---------------- bf16 epilogue: stage half-tile rows [h*128, h*128+128) ----------------
// MODE 0: v += bias ; MODE 2: v = exp(min(v*scale,30)) ; MODE 3: v *= rcp(rl[row])
template<int MODE>
__device__ __forceinline__ void epi_bf16(
    unsigned short* Ls, f32x4 (&acc)[8][4], int h,
    const unsigned short* bias_n0, const float* rlbase, float scale,
    unsigned short* Cg, int ldc)
{
  const int t = threadIdx.x, w = t >> 6, lane = t & 63;
  const int lo = lane & 15, quad = lane >> 4, wr = w >> 2, wcn = w & 3;
  __syncthreads();
  if (wr == h) {
    float bvv[4];
    if (MODE == 0) {
#pragma unroll
      for (int nf = 0; nf < 4; ++nf) bvv[nf] = b2f(bias_n0[wcn * 64 + nf * 16 + lo]);
    }
#pragma unroll
    for (int mf = 0; mf < 8; ++mf) {
      const int r0 = mf * 16 + quad * 4;
      float rv[4];
      if (MODE == 3) {
#pragma unroll
        for (int r = 0; r < 4; ++r) rv[r] = __builtin_amdgcn_rcpf(rlbase[h * 128 + r0 + r]);
      }
#pragma unroll
      for (int nf = 0; nf < 4; ++nf) {
        const int col = wcn * 64 + nf * 16 + lo;
#pragma unroll
        for (int r = 0; r < 4; ++r) {
          float v = acc[mf][nf][r];
          if (MODE == 0)      v += bvv[nf];
          else if (MODE == 2) v = __expf(fminf(v * scale, 30.f));
          else if (MODE == 3) v *= rv[r];
          Ls[(r0 + r) * 264 + col] = f2b(v);
        }
      }
    }
  }
  __syncthreads();
#pragma unroll
  for (int u0 = 0; u0 < 8; ++u0) {
    const int u = u0 * 512 + t, row = u >> 5, c16 = (u & 31) * 8;
    *(uint4*)(Cg + (size_t)(h * 128 + row) * ldc + c16) = *(const uint4*)(Ls + row * 264 + c16);
  }
}

// ---------------- qkv: fused projections ----------------
__global__ __launch_bounds__(512, 2) void qkv_k(
    const unsigned short* __restrict__ xb,
    const unsigned short* __restrict__ Wq, const unsigned short* __restrict__ bq,
    const unsigned short* __restrict__ Wk, const unsigned short* __restrict__ bk,
    const unsigned short* __restrict__ Wv, const unsigned short* __restrict__ bv,
    unsigned short* __restrict__ qb, unsigned short* __restrict__ kb,
    unsigned short* __restrict__ vt)
{
  __shared__ unsigned short smem[65536];
  const int sel = blockIdx.y / 3;
  const int n0  = (blockIdx.y % 3) * 256;
  const int m0  = blockIdx.x * 256;

  const unsigned short* W;
  const unsigned short* bi;
  if (sel == 0)      { W = Wq; bi = bq; }
  else if (sel == 1) { W = Wk; bi = bk; }
  else               { W = Wv; bi = bv; }

  f32x4 acc[8][4] = {};
  gemm256(xb + (size_t)m0 * 768, W + (size_t)n0 * 768, 768, 768, 12, smem, acc);

  if (sel < 2) {
    unsigned short* dst = (sel == 0 ? qb : kb) + (size_t)m0 * 768 + n0;
    epi_bf16<0>(smem, acc, 0, bi + n0, nullptr, 0.f, dst, 768);
    epi_bf16<0>(smem, acc, 1, bi + n0, nullptr, 0.f, dst, 768);
    return;
  }

  // V: transposed epilogue into Vt[b][e][s]; Ls as [e_local 128][s 264]
  const int t = threadIdx.x, w = t >> 6, lane = t & 63;
  const int lo = lane & 15, quad = lane >> 4, wr = w >> 2, wcn = w & 3;
  const int bb2 = m0 >> 11, sin = m0 & 2047;
  unsigned short* Ls = smem;
#pragma unroll
  for (int eh = 0; eh < 2; ++eh) {
    __syncthreads();
    if ((wcn >> 1) == eh) {
#pragma unroll
      for (int mf = 0; mf < 8; ++mf) {
        const int row = wr * 128 + mf * 16 + quad * 4;
#pragma unroll
        for (int nf = 0; nf < 4; ++nf) {
          const int colL = (wcn & 1) * 64 + nf * 16 + lo;
          const float bvv = b2f(bi[n0 + eh * 128 + colL]);
          ushort4 pk;
          pk.x = f2b(acc[mf][nf][0] + bvv);
          pk.y = f2b(acc[mf][nf][1] + bvv);
          pk.z = f2b(acc[mf][nf][2] + bvv);
          pk.w = f2b(acc[mf][nf][3] + bvv);
          *(ushort4*)(Ls + colL * 264 + row) = pk;
        }
      }
    }
    __syncthreads();
    unsigned short* Vb = vt + (size_t)bb2 * 1572864 + (size_t)(n0 + eh * 128) * 2048 + sin;
#pragma unroll
    for (int u0 = 0; u0 < 8; ++u0) {
      const int u = u0 * 512 + t, e = u >> 5, s16 = (u & 31) * 8;
      *(uint4*)(Vb + (size_t)e * 2048 + s16) = *(const uint4*)(Ls + e * 264 + s16);
    }
  }
}

// ---------------- score: E = exp(QK^T/sqrt(D)) + fused rowsum ----------------
__global__ __launch_bounds__(512, 2) void score_k(
    const unsigned short* __restrict__ Q, const unsigned short* __restrict__ Kb,
    unsigned short* __restrict__ E, float* __restrict__ rl, float scale)
{
  __shared__ unsigned short smem[65536];
  const int m0 = blockIdx.x * 256, n0 = blockIdx.y * 256, bz = blockIdx.z;

  f32x4 acc[8][4] = {};
  gemm256(Q + (size_t)bz * 1572864 + (size_t)m0 * 768,
          Kb + (size_t)bz * 1572864 + (size_t)n0 * 768, 768, 768, 12, smem, acc);

  const int t = threadIdx.x;
  unsigned short* Eg = E + (size_t)bz * 4194304 + (size_t)m0 * 2048 + n0;
#pragma unroll
  for (int h = 0; h < 2; ++h) {
    epi_bf16<2>(smem, acc, h, nullptr, nullptr, scale, Eg, 2048);
    // fused partial rowsum from staged LDS tile (4 threads/row, rotated reads)
    const int row = t >> 2, seg = t & 3;
    const unsigned short* lr = smem + row * 264 + seg * 64;
    float s = 0.f;
#pragma unroll
    for (int q8 = 0; q8 < 8; ++q8) {
      const int qq = ((q8 + row) & 7) * 8;
      uint4 v = *(const uint4*)(lr + qq);
      unsigned int uu[4] = {v.x, v.y, v.z, v.w};
#pragma unroll
      for (int c = 0; c < 4; ++c)
        s += b2f((unsigned short)(uu[c] & 0xffffu)) + b2f((unsigned short)(uu[c] >> 16));
    }
    s += __shfl_xor(s, 1);
    s += __shfl_xor(s, 2);
    if (seg == 0) atomicAdd(rl + bz * 2048 + m0 + h * 128 + row, s);
  }
}

// ---------------- pv: attn = (E @ V) * rcp(rowsum) ----------------
__global__ __launch_bounds__(512, 2) void pv_k(
    const unsigned short* __restrict__ E, const unsigned short* __restrict__ Vt,
    const float* __restrict__ rl, unsigned short* __restrict__ attn)
{
  __shared__ unsigned short smem[65536];
  const int m0 = blockIdx.x * 256, n0 = blockIdx.y * 256, bz = blockIdx.z;

  f32x4 acc[8][4] = {};
  gemm256(E + (size_t)bz * 4194304 + (size_t)m0 * 2048,
          Vt + (size_t)bz * 1572864 + (size_t)n0 * 2048, 2048, 2048, 32, smem, acc);

  const float* rlb = rl + bz * 2048 + m0;
  unsigned short* Cg = attn + (size_t)bz * 1572864 + (size_t)m0 * 768 + n0;
  epi_bf16<3>(smem, acc, 0, nullptr, rlb, 0.f, Cg, 768);
  epi_bf16<3>(smem, acc, 1, nullptr, rlb, 0.f, Cg, 768);
}

// ---------------- out: final projection (fp32 output) ----------------
__global__ __launch_bounds__(512, 2) void out_k(
    const unsigned short* __restrict__ attn,
    const unsigned short* __restrict__ Wp, const unsigned short* __restrict__ bp,
    float* __restrict__ Of)
{
  __shared__ unsigned short smem[65536];
  const int m0 = blockIdx.x * 256, n0 = blockIdx.y * 256;

  f32x4 acc[8][4] = {};
  gemm256(attn + (size_t)m0 * 768, Wp + (size_t)n0 * 768, 768, 768, 12, smem, acc);

  const int t = threadIdx.x, w = t >> 6, lane = t & 63;
  const int lo = lane & 15, quad = lane >> 4, wr = w >> 2, wcn = w & 3;
  float* Lf = (float*)smem;  // [64][264] floats per pass
#pragma unroll
  for (int p = 0; p < 4; ++p) {
    __syncthreads();
    if (wr == (p >> 1)) {
#pragma unroll
      for (int mi = 0; mi < 4; ++mi) {
        const int mf = (p & 1) * 4 + mi;
        const int r0 = mi * 16 + quad * 4;
#pragma unroll
        for (int nf = 0; nf < 4; ++nf) {
          const int col = wcn * 64 + nf * 16 + lo;
          const float bvv = b2f(bp[n0 + col]);
#pragma unroll
          for (int r = 0; r < 4; ++r)
            Lf[(r0 + r) * 264 + col] = acc[mf][nf][r] + bvv;
        }
      }
    }
    __syncthreads();
#pragma unroll
    for (int u0 = 0; u0 < 8; ++u0) {
      const int u = u0 * 512 + t, row = u >> 6, c4 = (u & 63) * 4;
      *(float4*)(Of + (size_t)(m0 + p * 64 + row) * 768 + n0 + c4) =
          *(const float4*)(Lf + row * 264 + c4);
    }
  }
}

extern "C" void kernel_launch(void* const* d_in, const int* in_sizes, int n_in,
                              void* d_out, int out_size, void* d_ws, size_t ws_size,
                              hipStream_t stream) {
  (void)in_sizes; (void)n_in; (void)out_size; (void)ws_size;

  char* ws = (char*)d_ws;
  float* rl    = (float*)(ws + 4096);
  unsigned short* wcv = (unsigned short*)(ws + ((size_t)1 << 20));
  unsigned short* qb  = (unsigned short*)(ws + ((size_t)8  << 20));
  unsigned short* kb  = (unsigned short*)(ws + ((size_t)32 << 20));
  unsigned short* vt  = (unsigned short*)(ws + ((size_t)56 << 20));
  unsigned short* eb  = (unsigned short*)(ws + ((size_t)80 << 20));
  unsigned short* xb  = eb;     // converted x aliases E (x dead before score_k writes E)
  unsigned short* attn = qb;    // Q dead after score_k

  unsigned short* wqb = wcv;
  unsigned short* bqb = wcv + 589824;
  unsigned short* wkb = wcv + 590592;
  unsigned short* bkb = wcv + 1180416;
  unsigned short* wvb = wcv + 1181184;
  unsigned short* bvb = wcv + 1771008;
  unsigned short* wpb = wcv + 1771776;
  unsigned short* bpb = wcv + 2361600;

  const float inv_scale = 0.036084391824351615f;  // 1/sqrt(768)

  Cvt9 cv;
  cv.s[0] = d_in[0]; cv.d[0] = xb;  cv.n8[0] = 12582912 / 8;
  cv.s[1] = d_in[1]; cv.d[1] = wqb; cv.n8[1] = 589824 / 8;
  cv.s[2] = d_in[2]; cv.d[2] = bqb; cv.n8[2] = 768 / 8;
  cv.s[3] = d_in[3]; cv.d[3] = wkb; cv.n8[3] = 589824 / 8;
  cv.s[4] = d_in[4]; cv.d[4] = bkb; cv.n8[4] = 768 / 8;
  cv.s[5] = d_in[5]; cv.d[5] = wvb; cv.n8[5] = 589824 / 8;
  cv.s[6] = d_in[6]; cv.d[6] = bvb; cv.n8[6] = 768 / 8;
  cv.s[7] = d_in[7]; cv.d[7] = wpb; cv.n8[7] = 589824 / 8;
  cv.s[8] = d_in[8]; cv.d[8] = bpb; cv.n8[8] = 768 / 8;
  cv.total8 = (12582912 + 4 * (589824 + 768)) / 8;
  convert_inputs<<<(unsigned)((cv.total8 + 255) / 256), dim3(256), 0, stream>>>(cv);

  hipMemsetAsync(rl, 0, 16384 * sizeof(float), stream);

  qkv_k<<<dim3(64, 9, 1), dim3(512), 0, stream>>>(xb, wqb, bqb, wkb, bkb, wvb, bvb, qb, kb, vt);

  score_k<<<dim3(8, 8, 8), dim3(512), 0, stream>>>(qb, kb, eb, rl, inv_scale);

  pv_k<<<dim3(8, 3, 8), dim3(512), 0, stream>>>(eb, vt, rl, attn);

  out_k<<<dim3(64, 3, 1), dim3(512), 0, stream>>>(attn, wpb, bpb, (float*)d_out);
}

// Round 3
// 321.040 us; speedup vs baseline: 1.1064x; 1.1022x over previous
//
#include <hip/hip_runtime.h>
#include <stdint.h>

// MultiHeadAttention  B=8, S=2048, D=768  (fp32 in/out; bf16 MFMA compute)
//
// Pipeline:
//   convert : all 9 fp32 inputs -> bf16 in ws
//   qkv_k   : fused Q/K/V projections (grid 64x12, N-tile 192); Vt[b][e][s]
//   score_k : E = exp(min(Q.K^T/sqrt(D),30)) bf16 + fused rowsum atomicAdd -> rl
//   pv_k    : attn = (E @ V) * rcp(rl)   (grid 256, N-tile 192)
//   out_k   : out = attn@Wp^T + bp fp32  (grid 256, N-tile 192)
//
// 256xN / BK=64 / 8-wave / 4-phase GEMM core, templated NQ = Ntile/64 in {3,4}.
// *** This round: grid quantization fix ***
// R2 model closure: per-block core quality ~56-60% (near m201-grade given
// K=768's short loop); dominant loss = grid tail at 1 block/CU (VGPR+LDS pin
// occupancy): qkv 576 blocks = 3 rounds for 2.25 rounds of work (x1.33,
// OccupancyPercent 15.8% vs structural 25%); pv/out 192 blocks = 0.75 round.
// Retile N=768 as 4x192 (NQ=3): qkv 768 blocks = 3.0 exact rounds, pv/out 256
// blocks = 1.0 exact round. score_k stays NQ=4 (512 = 2.0 exact rounds).

typedef __attribute__((ext_vector_type(8))) short short8;
typedef __attribute__((ext_vector_type(4))) float f32x4;

typedef const __attribute__((address_space(1))) void gvoid_t;
typedef __attribute__((address_space(3))) void lvoid_t;

__device__ __forceinline__ float b2f(unsigned short u) {
  union { unsigned int u; float f; } v;
  v.u = ((unsigned int)u) << 16;
  return v.f;
}
__device__ __forceinline__ unsigned short f2b(float f) {
  union { float f; unsigned int u; } v; v.f = f;
  unsigned int u = v.u;
  return (unsigned short)((u + 0x7fffu + ((u >> 16) & 1u)) >> 16);
}

// ---------------- fp32 -> bf16 conversion ----------------
struct Cvt9 {
  const void* s[9];
  unsigned short* d[9];
  long long n8[9];
  long long total8;
};

__global__ __launch_bounds__(256) void convert_inputs(Cvt9 C) {
  long long g = (long long)blockIdx.x * 256 + threadIdx.x;
  if (g >= C.total8) return;
  int s = 0;
  long long off = g;
  while (off >= C.n8[s]) { off -= C.n8[s]; ++s; }
  const float* sf = (const float*)C.s[s] + off * 8;
  unsigned short* dp = C.d[s] + off * 8;
  float4 a = ((const float4*)sf)[0];
  float4 b = ((const float4*)sf)[1];
  uint4 o;
  o.x = (unsigned int)f2b(a.x) | ((unsigned int)f2b(a.y) << 16);
  o.y = (unsigned int)f2b(a.z) | ((unsigned int)f2b(a.w) << 16);
  o.z = (unsigned int)f2b(b.x) | ((unsigned int)f2b(b.y) << 16);
  o.w = (unsigned int)f2b(b.z) | ((unsigned int)f2b(b.w) << 16);
  *(uint4*)dp = o;
}

// ---------------- 256x(64*NQ) 4-phase GEMM core ----------------
// C[m0..+256][n0..+64NQ] += A[m0..][0..K) . B[n0..][0..K)^T  (both NT-major, bf16)
// LDS buffer b at b*(4+NQ)*8192 B: A 256x64 (32768 B), then B (64NQ)x64.
// Quarter (64 rows) = 8192 B staging unit; 8-slot rotation swizzle
// (src slot = (t&7)^((t>>3)&7); read slot = kc-chunk ^ (row&7)) -> 2-way free.
template<int NQ>
__device__ __forceinline__ void gemm256(
    const unsigned short* __restrict__ Ag,   // pre-offset to (m0, 0), lda shorts
    const unsigned short* __restrict__ Bg,   // pre-offset to (n0, 0), ldb shorts
    const int lda, const int ldb, const int NT,
    unsigned short* lds, f32x4 (&acc)[8][NQ])
{
  const int t    = threadIdx.x;
  const int w    = t >> 6;
  const int lane = t & 63;
  const int lo   = lane & 15;
  const int quad = lane >> 4;
  const int wr   = w >> 2;          // 0..1  (row half of C tile)
  const int wcn  = w & 3;           // 0..3  (col quarter of C tile)
  const int swz  = ((t & 7) ^ ((t >> 3) & 7)) << 3;   // pre-swizzled src k-slot (shorts)
  const int wslot = w * 512;                          // wave slot in a stage round (shorts)
  constexpr int SBUF_B = (4 + NQ) * 8192;             // buffer stride bytes
  constexpr int SBUF_S = SBUF_B / 2;                  // shorts

  const unsigned lbase = (unsigned)(uintptr_t)(void*)lds;
  const unsigned sb0 = (unsigned)((quad ^ (lo & 7)) << 4);        // k-chunk 0 slot (bytes)
  const unsigned sb1 = (unsigned)(((4 + quad) ^ (lo & 7)) << 4);  // k-chunk 1 slot (bytes)
  const unsigned aA0 = lbase + wr * 16384 + lo * 128 + sb0;
  const unsigned aA1 = lbase + wr * 16384 + lo * 128 + sb1;
  const unsigned bB  = lbase + 32768u + (unsigned)(wcn * 16 * NQ + lo) * 128;
  const unsigned aB0 = bB + sb0;
  const unsigned aB1 = bB + sb1;

  short8 af[4][2], bf0[2][2], bf1[2][2];

#define STG(gb, ld, kt, q, reg)                                                   \
  __builtin_amdgcn_global_load_lds(                                               \
      (gvoid_t*)((gb) + (size_t)((q) * 64 + (t >> 3)) * (ld) + (kt) * 64 + swz),  \
      (lvoid_t*)((reg) + wslot), 16, 0, 0)
#define SA02(kt) { unsigned short* r_ = lds + ((kt) & 1) * SBUF_S;         \
                   STG(Ag, lda, (kt), 0, r_); STG(Ag, lda, (kt), 2, r_ + 8192); }
#define SA13(kt) { unsigned short* r_ = lds + ((kt) & 1) * SBUF_S;         \
                   STG(Ag, lda, (kt), 1, r_ + 4096); STG(Ag, lda, (kt), 3, r_ + 12288); }
#define SBALL(kt) { unsigned short* r_ = lds + ((kt) & 1) * SBUF_S + 16384; \
                    STG(Bg, ldb, (kt), 0, r_); STG(Bg, ldb, (kt), 1, r_ + 4096); \
                    STG(Bg, ldb, (kt), 2, r_ + 8192); \
                    if constexpr (NQ == 4) STG(Bg, ldb, (kt), 3, r_ + 12288); }
// inline-asm LDS fragment read: invisible to the memory legalizer (no auto vmcnt)
#define DSR(d, a, IMM) asm volatile("ds_read_b128 %0, %1 offset:" #IMM : "=v"(d) : "v"(a))
#define RDA(MH, bo) {                                                 \
  const unsigned a0_ = aA0 + (bo) + (MH) * 8192;                      \
  const unsigned a1_ = aA1 + (bo) + (MH) * 8192;                      \
  DSR(af[0][0], a0_, 0);    DSR(af[0][1], a1_, 0);                    \
  DSR(af[1][0], a0_, 2048); DSR(af[1][1], a1_, 2048);                 \
  DSR(af[2][0], a0_, 4096); DSR(af[2][1], a1_, 4096);                 \
  DSR(af[3][0], a0_, 6144); DSR(af[3][1], a1_, 6144); }
#define RDB(BF, NB, NFR, bo) {                                        \
  const unsigned b0_ = aB0 + (bo) + (NB) * 2048;                      \
  const unsigned b1_ = aB1 + (bo) + (NB) * 2048;                      \
  DSR(BF[0][0], b0_, 0);    DSR(BF[0][1], b1_, 0);                    \
  if ((NFR) == 2) { DSR(BF[1][0], b0_, 2048); DSR(BF[1][1], b1_, 2048); } }
#define MMA(MH, NB, BF, NFR) {                                                \
  __builtin_amdgcn_s_barrier();                                               \
  asm volatile("s_waitcnt lgkmcnt(0)" ::: "memory");                          \
  __builtin_amdgcn_sched_barrier(0);                                          \
  __builtin_amdgcn_s_setprio(1);                                              \
  _Pragma("unroll") for (int kc = 0; kc < 2; ++kc)                            \
  _Pragma("unroll") for (int mi = 0; mi < 4; ++mi)                            \
  _Pragma("unroll") for (int ni = 0; ni < (NFR); ++ni)                        \
    acc[(MH)*4 + mi][(NB) + ni] = __builtin_amdgcn_mfma_f32_16x16x32_bf16(    \
        af[mi][kc], BF[ni][kc], acc[(MH)*4 + mi][(NB) + ni], 0, 0, 0);        \
  __builtin_amdgcn_s_setprio(0);                                              \
  __builtin_amdgcn_sched_barrier(0);                                          \
  __builtin_amdgcn_s_barrier(); }
#define VMS() { if constexpr (NQ == 4) asm volatile("s_waitcnt vmcnt(8)" ::: "memory"); \
                else                   asm volatile("s_waitcnt vmcnt(7)" ::: "memory"); }
#define VM0() asm volatile("s_waitcnt vmcnt(0)" ::: "memory")

  // prologue: tiles 0 and 1 fully staged; wait tile 0 (tile 1 stays in flight)
  SA02(0); SBALL(0); SA13(0);
  SA02(1); SBALL(1); SA13(1);
  VMS();
  __builtin_amdgcn_s_barrier();

  // steady state: each quarter staged exactly one phase after its last read.
  // Invariant at iter entry: (4+NQ) outstanding = all of tile kt+1.
  for (int kt = 0; kt < NT - 2; ++kt) {
    const unsigned bo = (unsigned)((kt & 1) * SBUF_B);
    // ph1: reads A02(kt) + B frags 0,1
    RDA(0, bo); RDB(bf0, 0, 2, bo);                       MMA(0, 0, bf0, 2);
    // ph2: reads B frags 2(,3); stage A02(kt+2) (A02 last read ph1)
    RDB(bf1, 2, NQ - 2, bo); SA02(kt + 2);                MMA(0, 2, bf1, NQ - 2);
    // ph3: reads A13(kt); stage all B(kt+2) (B last read ph2)
    RDA(1, bo); SBALL(kt + 2);                            MMA(1, 0, bf0, 2);
    // ph4: stage A13(kt+2) (A13 last read ph3); wait tile kt+1 complete
    SA13(kt + 2); VMS();                                  MMA(1, 2, bf1, NQ - 2);
  }
  { // kt = NT-2: no staging; drain remaining (tile NT-1) at ph4
    const unsigned bo = (unsigned)((NT & 1) * SBUF_B);    // (NT-2)&1 == NT&1
    RDA(0, bo); RDB(bf0, 0, 2, bo);                       MMA(0, 0, bf0, 2);
    RDB(bf1, 2, NQ - 2, bo);                              MMA(0, 2, bf1, NQ - 2);
    RDA(1, bo);                                           MMA(1, 0, bf0, 2);
    VM0();                                                MMA(1, 2, bf1, NQ - 2);
  }
  { // kt = NT-1: all data resident
    const unsigned bo = (unsigned)(((NT - 1) & 1) * SBUF_B);
    RDA(0, bo); RDB(bf0, 0, 2, bo);                       MMA(0, 0, bf0, 2);
    RDB(bf1, 2, NQ - 2, bo);                              MMA(0, 2, bf1, NQ - 2);
    RDA(1, bo);                                           MMA(1, 0, bf0, 2);
                                                          MMA(1, 2, bf1, NQ - 2);
  }
#undef STG
#undef SA02
#undef SA13
#undef SBALL
#undef DSR
#undef RDA
#undef RDB
#undef MMA
#undef VMS
#undef VM0
}

// ---------------- bf16 epilogue: stage half-tile rows [h*128, h*128+128) ----------------
// MODE 0: v += bias ; MODE 2: v = exp(min(v*scale,30)) ; MODE 3: v *= rcp(rl[row])
template<int MODE, int NQ>
__device__ __forceinline__ void epi_bf16(
    unsigned short* Ls, f32x4 (&acc)[8][NQ], int h,
    const unsigned short* bias_n0, const float* rlbase, float scale,
    unsigned short* Cg, int ldc)
{
  constexpr int RS = 64 * NQ + 8;   // LDS row stride (shorts), 16B-aligned
  const int t = threadIdx.x, w = t >> 6, lane = t & 63;
  const int lo = lane & 15, quad = lane >> 4, wr = w >> 2, wcn = w & 3;
  __syncthreads();
  if (wr == h) {
    float bvv[NQ];
    if (MODE == 0) {
#pragma unroll
      for (int nf = 0; nf < NQ; ++nf) bvv[nf] = b2f(bias_n0[wcn * 16 * NQ + nf * 16 + lo]);
    }
#pragma unroll
    for (int mf = 0; mf < 8; ++mf) {
      const int r0 = mf * 16 + quad * 4;
      float rv[4];
      if (MODE == 3) {
#pragma unroll
        for (int r = 0; r < 4; ++r) rv[r] = __builtin_amdgcn_rcpf(rlbase[h * 128 + r0 + r]);
      }
#pragma unroll
      for (int nf = 0; nf < NQ; ++nf) {
        const int col = wcn * 16 * NQ + nf * 16 + lo;
#pragma unroll
        for (int r = 0; r < 4; ++r) {
          float v = acc[mf][nf][r];
          if (MODE == 0)      v += bvv[nf];
          else if (MODE == 2) v = __expf(fminf(v * scale, 30.f));
          else if (MODE == 3) v *= rv[r];
          Ls[(r0 + r) * RS + col] = f2b(v);
        }
      }
    }
  }
  __syncthreads();
#pragma unroll
  for (int u0 = 0; u0 < 2 * NQ; ++u0) {
    const int u = u0 * 512 + t, row = u / (8 * NQ), c16 = (u % (8 * NQ)) * 8;
    *(uint4*)(Cg + (size_t)(h * 128 + row) * ldc + c16) = *(const uint4*)(Ls + row * RS + c16);
  }
}

// ---------------- qkv: fused projections (N-tile 192) ----------------
__global__ __launch_bounds__(512, 2) void qkv_k(
    const unsigned short* __restrict__ xb,
    const unsigned short* __restrict__ Wq, const unsigned short* __restrict__ bq,
    const unsigned short* __restrict__ Wk, const unsigned short* __restrict__ bk,
    const unsigned short* __restrict__ Wv, const unsigned short* __restrict__ bv,
    unsigned short* __restrict__ qb, unsigned short* __restrict__ kb,
    unsigned short* __restrict__ vt)
{
  __shared__ unsigned short smem[57344];   // 114688 B = 2 x (4+3)*8192
  const int sel = blockIdx.y >> 2;
  const int n0  = (blockIdx.y & 3) * 192;
  const int m0  = blockIdx.x * 256;

  const unsigned short* W;
  const unsigned short* bi;
  if (sel == 0)      { W = Wq; bi = bq; }
  else if (sel == 1) { W = Wk; bi = bk; }
  else               { W = Wv; bi = bv; }

  f32x4 acc[8][3] = {};
  gemm256<3>(xb + (size_t)m0 * 768, W + (size_t)n0 * 768, 768, 768, 12, smem, acc);

  if (sel < 2) {
    unsigned short* dst = (sel == 0 ? qb : kb) + (size_t)m0 * 768 + n0;
    epi_bf16<0, 3>(smem, acc, 0, bi + n0, nullptr, 0.f, dst, 768);
    epi_bf16<0, 3>(smem, acc, 1, bi + n0, nullptr, 0.f, dst, 768);
    return;
  }

  // V: transposed epilogue into Vt[b][e][s]; 3 e-chunks of 64, Ls [64][264]
  const int t = threadIdx.x, w = t >> 6, lane = t & 63;
  const int lo = lane & 15, quad = lane >> 4, wr = w >> 2, wcn = w & 3;
  const int bb2 = m0 >> 11, sin = m0 & 2047;
  unsigned short* Ls = smem;
#pragma unroll
  for (int ec = 0; ec < 3; ++ec) {
    __syncthreads();
#pragma unroll
    for (int nf = 0; nf < 3; ++nf) {
      const int ebase = wcn * 48 + nf * 16;
      if ((ebase >> 6) == ec) {
        const float bvv = b2f(bi[n0 + ebase + lo]);
#pragma unroll
        for (int mf = 0; mf < 8; ++mf) {
          const int srow = wr * 128 + mf * 16 + quad * 4;
          ushort4 pk;
          pk.x = f2b(acc[mf][nf][0] + bvv);
          pk.y = f2b(acc[mf][nf][1] + bvv);
          pk.z = f2b(acc[mf][nf][2] + bvv);
          pk.w = f2b(acc[mf][nf][3] + bvv);
          *(ushort4*)(Ls + ((ebase & 63) + lo) * 264 + srow) = pk;
        }
      }
    }
    __syncthreads();
    unsigned short* Vb = vt + (size_t)bb2 * 1572864 + (size_t)(n0 + ec * 64) * 2048 + sin;
#pragma unroll
    for (int u0 = 0; u0 < 4; ++u0) {
      const int u = u0 * 512 + t, e = u >> 5, s16 = (u & 31) * 8;
      *(uint4*)(Vb + (size_t)e * 2048 + s16) = *(const uint4*)(Ls + e * 264 + s16);
    }
  }
}

// ---------------- score: E = exp(QK^T/sqrt(D)) + fused rowsum (N-tile 256) ----------------
__global__ __launch_bounds__(512, 2) void score_k(
    const unsigned short* __restrict__ Q, const unsigned short* __restrict__ Kb,
    unsigned short* __restrict__ E, float* __restrict__ rl, float scale)
{
  __shared__ unsigned short smem[65536];
  const int m0 = blockIdx.x * 256, n0 = blockIdx.y * 256, bz = blockIdx.z;

  f32x4 acc[8][4] = {};
  gemm256<4>(Q + (size_t)bz * 1572864 + (size_t)m0 * 768,
             Kb + (size_t)bz * 1572864 + (size_t)n0 * 768, 768, 768, 12, smem, acc);

  const int t = threadIdx.x;
  unsigned short* Eg = E + (size_t)bz * 4194304 + (size_t)m0 * 2048 + n0;
#pragma unroll
  for (int h = 0; h < 2; ++h) {
    epi_bf16<2, 4>(smem, acc, h, nullptr, nullptr, scale, Eg, 2048);
    // fused partial rowsum from staged LDS tile (4 threads/row, rotated reads)
    const int row = t >> 2, seg = t & 3;
    const unsigned short* lr = smem + row * 264 + seg * 64;
    float s = 0.f;
#pragma unroll
    for (int q8 = 0; q8 < 8; ++q8) {
      const int qq = ((q8 + row) & 7) * 8;
      uint4 v = *(const uint4*)(lr + qq);
      unsigned int uu[4] = {v.x, v.y, v.z, v.w};
#pragma unroll
      for (int c = 0; c < 4; ++c)
        s += b2f((unsigned short)(uu[c] & 0xffffu)) + b2f((unsigned short)(uu[c] >> 16));
    }
    s += __shfl_xor(s, 1);
    s += __shfl_xor(s, 2);
    if (seg == 0) atomicAdd(rl + bz * 2048 + m0 + h * 128 + row, s);
  }
}

// ---------------- pv: attn = (E @ V) * rcp(rowsum) (N-tile 192) ----------------
__global__ __launch_bounds__(512, 2) void pv_k(
    const unsigned short* __restrict__ E, const unsigned short* __restrict__ Vt,
    const float* __restrict__ rl, unsigned short* __restrict__ attn)
{
  __shared__ unsigned short smem[57344];
  const int m0 = blockIdx.x * 256, n0 = blockIdx.y * 192, bz = blockIdx.z;

  f32x4 acc[8][3] = {};
  gemm256<3>(E + (size_t)bz * 4194304 + (size_t)m0 * 2048,
             Vt + (size_t)bz * 1572864 + (size_t)n0 * 2048, 2048, 2048, 32, smem, acc);

  const float* rlb = rl + bz * 2048 + m0;
  unsigned short* Cg = attn + (size_t)bz * 1572864 + (size_t)m0 * 768 + n0;
  epi_bf16<3, 3>(smem, acc, 0, nullptr, rlb, 0.f, Cg, 768);
  epi_bf16<3, 3>(smem, acc, 1, nullptr, rlb, 0.f, Cg, 768);
}

// ---------------- out: final projection (fp32 output, N-tile 192) ----------------
__global__ __launch_bounds__(512, 2) void out_k(
    const unsigned short* __restrict__ attn,
    const unsigned short* __restrict__ Wp, const unsigned short* __restrict__ bp,
    float* __restrict__ Of)
{
  __shared__ unsigned short smem[57344];
  const int m0 = blockIdx.x * 256, n0 = blockIdx.y * 192;

  f32x4 acc[8][3] = {};
  gemm256<3>(attn + (size_t)m0 * 768, Wp + (size_t)n0 * 768, 768, 768, 12, smem, acc);

  // fp32 output: 4 chunks of 64 rows staged as float through LDS [64][196]
  const int t = threadIdx.x, w = t >> 6, lane = t & 63;
  const int lo = lane & 15, quad = lane >> 4, wr = w >> 2, wcn = w & 3;
  float* Lf = (float*)smem;
#pragma unroll
  for (int p = 0; p < 4; ++p) {
    __syncthreads();
    if (wr == (p >> 1)) {
#pragma unroll
      for (int mi = 0; mi < 4; ++mi) {
        const int mf = (p & 1) * 4 + mi;
        const int r0 = mi * 16 + quad * 4;
#pragma unroll
        for (int nf = 0; nf < 3; ++nf) {
          const int col = wcn * 48 + nf * 16 + lo;
          const float bvv = b2f(bp[n0 + col]);
#pragma unroll
          for (int r = 0; r < 4; ++r)
            Lf[(r0 + r) * 196 + col] = acc[mf][nf][r] + bvv;
        }
      }
    }
    __syncthreads();
#pragma unroll
    for (int u0 = 0; u0 < 6; ++u0) {
      const int u = u0 * 512 + t, row = u / 48, c4 = (u % 48) * 4;
      *(float4*)(Of + (size_t)(m0 + p * 64 + row) * 768 + n0 + c4) =
          *(const float4*)(Lf + row * 196 + c4);
    }
  }
}

extern "C" void kernel_launch(void* const* d_in, const int* in_sizes, int n_in,
                              void* d_out, int out_size, void* d_ws, size_t ws_size,
                              hipStream_t stream) {
  (void)in_sizes; (void)n_in; (void)out_size; (void)ws_size;

  char* ws = (char*)d_ws;
  float* rl    = (float*)(ws + 4096);
  unsigned short* wcv = (unsigned short*)(ws + ((size_t)1 << 20));
  unsigned short* qb  = (unsigned short*)(ws + ((size_t)8  << 20));
  unsigned short* kb  = (unsigned short*)(ws + ((size_t)32 << 20));
  unsigned short* vt  = (unsigned short*)(ws + ((size_t)56 << 20));
  unsigned short* eb  = (unsigned short*)(ws + ((size_t)80 << 20));
  unsigned short* xb  = eb;     // converted x aliases E (x dead before score_k writes E)
  unsigned short* attn = qb;    // Q dead after score_k

  unsigned short* wqb = wcv;
  unsigned short* bqb = wcv + 589824;
  unsigned short* wkb = wcv + 590592;
  unsigned short* bkb = wcv + 1180416;
  unsigned short* wvb = wcv + 1181184;
  unsigned short* bvb = wcv + 1771008;
  unsigned short* wpb = wcv + 1771776;
  unsigned short* bpb = wcv + 2361600;

  const float inv_scale = 0.036084391824351615f;  // 1/sqrt(768)

  Cvt9 cv;
  cv.s[0] = d_in[0]; cv.d[0] = xb;  cv.n8[0] = 12582912 / 8;
  cv.s[1] = d_in[1]; cv.d[1] = wqb; cv.n8[1] = 589824 / 8;
  cv.s[2] = d_in[2]; cv.d[2] = bqb; cv.n8[2] = 768 / 8;
  cv.s[3] = d_in[3]; cv.d[3] = wkb; cv.n8[3] = 589824 / 8;
  cv.s[4] = d_in[4]; cv.d[4] = bkb; cv.n8[4] = 768 / 8;
  cv.s[5] = d_in[5]; cv.d[5] = wvb; cv.n8[5] = 589824 / 8;
  cv.s[6] = d_in[6]; cv.d[6] = bvb; cv.n8[6] = 768 / 8;
  cv.s[7] = d_in[7]; cv.d[7] = wpb; cv.n8[7] = 589824 / 8;
  cv.s[8] = d_in[8]; cv.d[8] = bpb; cv.n8[8] = 768 / 8;
  cv.total8 = (12582912 + 4 * (589824 + 768)) / 8;
  convert_inputs<<<(unsigned)((cv.total8 + 255) / 256), dim3(256), 0, stream>>>(cv);

  hipMemsetAsync(rl, 0, 16384 * sizeof(float), stream);

  qkv_k<<<dim3(64, 12, 1), dim3(512), 0, stream>>>(xb, wqb, bqb, wkb, bkb, wvb, bvb, qb, kb, vt);

  score_k<<<dim3(8, 8, 8), dim3(512), 0, stream>>>(qb, kb, eb, rl, inv_scale);

  pv_k<<<dim3(8, 4, 8), dim3(512), 0, stream>>>(eb, vt, rl, attn);

  out_k<<<dim3(64, 4, 1), dim3(512), 0, stream>>>(attn, wpb, bpb, (float*)d_out);
}